// Round 1
// baseline (211.267 us; speedup 1.0000x reference)
//
#include <hip/hip_runtime.h>

// Correlation via bf16 MFMA banded Gram.
// out[b, dyp*21+k, y, x] = (1/256) * sum_c in1[b,c,y,x] * in2[b,c,y+2(dyp-10), x+2(k-10)]
// Layouts (workspace): Ag/Bg[b*64+y][par*48+col][c] bf16, x = 2*col+par.
//
// R6 structure: main kernel goes 512-thread / 8-wave (par x 4 dyp-slots per round):
//  - rounds per block 6 -> 3 (halves the vmcnt-draining barriers)
//  - 16 waves/CU (4/SIMD) instead of 8 (2/SIMD) for latency hiding
//  - Bsh pad (BP=260) replaced by XOR swizzle (idx ^= (row&7)<<3) so
//    Bsh(49152) + scr[4](32592) = 81744 B <= 81920 B -> still 2 blocks/CU.

typedef short bf16x8 __attribute__((ext_vector_type(8)));
typedef float f32x4  __attribute__((ext_vector_type(4)));

#define PLANE 24576         // shorts per (b,y) plane: 96 rows * 256 c
#define ST    40            // prepass LDS row stride (shorts)

__device__ __forceinline__ short f2bf(float f) {
    union { float f; unsigned u; } x; x.f = f;
    const unsigned u = x.u;
    return (short)((u + 0x7fffu + ((u >> 16) & 1u)) >> 16);
}

// ---------- prepass: fp32 [b][c][y][x] -> bf16 [b*64+y][par*48+col][c] ----------
// block = (sel, b, ytile of 8, ctile of 32ch). Reads 3KB contiguous per channel.
__global__ __launch_bounds__(256)
void corr_prepass(const float* __restrict__ in1, const float* __restrict__ in2,
                  short* __restrict__ dstA, short* __restrict__ dstB) {
    const int bid = blockIdx.x;
    const int sel = bid >> 8;
    const int r   = bid & 255;
    const int b   = r >> 6;
    const int yt  = (r >> 3) & 7;
    const int ct  = r & 7;
    const int c0 = ct * 32, y0 = yt * 8;
    const float* src = sel ? in2 : in1;
    short* dst = sel ? dstB : dstA;

    __shared__ __align__(16) short T[768 * ST];   // [xx = yy*96+x][32c], 61.4 KB
    const int tid = threadIdx.x;

#pragma unroll
    for (int it = 0; it < 3; ++it) {
        const int d = it * 256 + tid;            // [0,768)
        const int g = d / 192;                   // channel octet 0..3
        const int f = d - g * 192;               // float4 index in 8y*96x chunk
        float4 v[8];
#pragma unroll
        for (int j = 0; j < 8; ++j) {
            const int c = c0 + g * 8 + j;
            v[j] = *(const float4*)(src + ((size_t)(b * 256 + c) * 64 + y0) * 96 + 4 * f);
        }
        bf16x8 w0, w1, w2, w3;
#pragma unroll
        for (int j = 0; j < 8; ++j) {
            w0[j] = f2bf(v[j].x); w1[j] = f2bf(v[j].y);
            w2[j] = f2bf(v[j].z); w3[j] = f2bf(v[j].w);
        }
        const int perm = ((g ^ (f & 3)) * 8);
        const int base = 4 * f * ST + perm;
        *(bf16x8*)&T[base]          = w0;
        *(bf16x8*)&T[base + ST]     = w1;
        *(bf16x8*)&T[base + 2*ST]   = w2;
        *(bf16x8*)&T[base + 3*ST]   = w3;
    }
    __syncthreads();

#pragma unroll
    for (int it = 0; it < 12; ++it) {
        const int D  = it * 256 + tid;           // [0,3072)
        const int Rl = D >> 2, gp = D & 3;
        const int yy  = Rl / 96;
        const int rl  = Rl - yy * 96;
        const int par = rl / 48;
        const int col = rl - par * 48;
        const int x   = 2 * col + par;
        const int xx  = yy * 96 + x;
        const int perm = ((gp ^ ((xx >> 2) & 3)) * 8);
        const bf16x8 w = *(const bf16x8*)&T[xx * ST + perm];
        const size_t Rg = (size_t)(b * 64 + y0 + yy) * 96 + par * 48 + col;
        *(bf16x8*)(dst + Rg * 256 + c0 + gp * 8) = w;
    }
}

// ---------- main kernel: 512 threads = 8 waves = par(2) x slot(4) ----------
__global__ __launch_bounds__(512, 4)
void corr_mfma(const short* __restrict__ Ag, const short* __restrict__ Bg,
               float* __restrict__ out) {
    const int bid = blockIdx.x;                  // [0,512)
    const int pg  = bid >> 8;
    const int by2 = bid & 255;
    const int b = by2 >> 6, y2 = by2 & 63;
    const int p0 = pg ? 3 : 0, p1 = pg ? 6 : 3;  // dyp = 4p+slot: pg0 0..11, pg1 12..23

    const int tid  = threadIdx.x;
    const int lane = tid & 63, w = tid >> 6;     // w in [0,8)
    const int par  = w & 1, slot = w >> 1;       // slot in [0,4)
    const int n    = lane & 15, q = lane >> 4;

    __shared__ __align__(16) short Bsh[96 * 256];    // 49152 B, XOR-swizzled rows
    __shared__ __align__(16) float scr[4][21 * 97];  // 32592 B

    // stage B(b,y2) ONCE (swizzled: short_idx ^= (row&7)<<3  ==  byte ^= (row&7)<<4)
    {
        const short* src = Bg + (size_t)by2 * PLANE;
#pragma unroll
        for (int it = 0; it < 6; ++it) {
            const int j   = it * 512 + tid;      // [0,3072)
            const int row = j >> 5;
            const int ofs = (row * 256 + (j & 31) * 8) ^ ((row & 7) << 3);
            *(bf16x8*)&Bsh[ofs] = *(const bf16x8*)(src + j * 8);
        }
    }
    __syncthreads();

    const bool v0 = (n >= 10), v3 = (n < 10);
    const int r0 = par * 48 + (v0 ? (n - 10) : 0);
    const int r1 = par * 48 + n + 6;
    const int r2 = par * 48 + n + 22;
    const int r3 = par * 48 + (v3 ? (n + 38) : 0);

    for (int p = p0; p < p1; ++p) {
        const int dyp = 4 * p + slot;
        const int y   = y2 + 20 - 2 * dyp;
        const bool live = (dyp < 21) && (y >= 0) && (y < 64);

        f32x4 acc[9];
#pragma unroll
        for (int t2 = 0; t2 < 9; ++t2) acc[t2] = (f32x4)0.0f;

        if (live) {
            // A-fragments direct from global (dense 64B-line gather, L2/L3-resident)
            const short* Ap = Ag + ((size_t)(b * 64 + y) * 96 + par * 48) * 256;
            bf16x8 af[3][8];
#pragma unroll
            for (int ks = 0; ks < 8; ++ks)
#pragma unroll
                for (int Xi = 0; Xi < 3; ++Xi)
                    af[Xi][ks] = *(const bf16x8*)(Ap + (Xi * 16 + n) * 256 + ks * 32 + q * 8);

#pragma unroll
            for (int ks = 0; ks < 8; ++ks) {
                const int ko = ks * 32 + q * 8;
                bf16x8 b0 = *(const bf16x8*)&Bsh[(r0 * 256 + ko) ^ ((r0 & 7) << 3)]; if (!v0) b0 = 0;
                bf16x8 b1 = *(const bf16x8*)&Bsh[(r1 * 256 + ko) ^ ((r1 & 7) << 3)];
                bf16x8 b2 = *(const bf16x8*)&Bsh[(r2 * 256 + ko) ^ ((r2 & 7) << 3)];
                bf16x8 b3 = *(const bf16x8*)&Bsh[(r3 * 256 + ko) ^ ((r3 & 7) << 3)]; if (!v3) b3 = 0;
                acc[0] = __builtin_amdgcn_mfma_f32_16x16x32_bf16(af[0][ks], b0, acc[0], 0, 0, 0);
                acc[1] = __builtin_amdgcn_mfma_f32_16x16x32_bf16(af[0][ks], b1, acc[1], 0, 0, 0);
                acc[2] = __builtin_amdgcn_mfma_f32_16x16x32_bf16(af[0][ks], b2, acc[2], 0, 0, 0);
                acc[3] = __builtin_amdgcn_mfma_f32_16x16x32_bf16(af[1][ks], b1, acc[3], 0, 0, 0);
                acc[4] = __builtin_amdgcn_mfma_f32_16x16x32_bf16(af[1][ks], b2, acc[4], 0, 0, 0);
                acc[5] = __builtin_amdgcn_mfma_f32_16x16x32_bf16(af[1][ks], b3, acc[5], 0, 0, 0);
                acc[6] = __builtin_amdgcn_mfma_f32_16x16x32_bf16(af[2][ks], b2, acc[6], 0, 0, 0);
                acc[7] = __builtin_amdgcn_mfma_f32_16x16x32_bf16(af[2][ks], b3, acc[7], 0, 0, 0);
                // acc[8] = (X2,U4): all B cols OOB -> stays zero (real zero outputs)
            }

            // scatter C tiles into scratch at (k, x=2*xe+par)
            float* sc = scr[slot];
            const int mb = q * 4;
#pragma unroll
            for (int t2 = 0; t2 < 9; ++t2) {
                const int Xi = (t2 < 3) ? 0 : (t2 < 6 ? 1 : 2);
                constexpr int UJ[9] = {0, 1, 2, 1, 2, 3, 2, 3, 4};
                const int ub = UJ[t2] * 16;
#pragma unroll
                for (int rr = 0; rr < 4; ++rr) {
                    const int xe = Xi * 16 + mb + rr;
                    const int k  = ub + n - xe;
                    if ((unsigned)k < 21u)
                        sc[k * 97 + 2 * xe + par] = acc[t2][rr];
                }
            }
        }
        __syncthreads();

        // cooperative coalesced store of all 4 slots' dyps
#pragma unroll
        for (int it = 0; it < 16; ++it) {
            const int e = it * 512 + tid;        // [0,8192), valid < 8064
            if (e < 8064) {
                const int s  = e / 2016;
                const int f  = e - s * 2016;
                const int k  = f / 96;
                const int x  = f - k * 96;
                const int dd = 4 * p + s;
                const int yd = y2 + 20 - 2 * dd;
                if (dd < 21 && yd >= 0 && yd < 64)
                    out[((size_t)(b * 441 + dd * 21 + k) * 64 + yd) * 96 + x] =
                        scr[s][k * 97 + x] * (1.0f / 256.0f);
            }
        }
        __syncthreads();
    }
}

extern "C" void kernel_launch(void* const* d_in, const int* in_sizes, int n_in,
                              void* d_out, int out_size, void* d_ws, size_t ws_size,
                              hipStream_t stream) {
    const float* in1 = (const float*)d_in[0];
    const float* in2 = (const float*)d_in[1];
    float* out = (float*)d_out;

    short* Ag = (short*)d_ws;                    // 256 planes * 24576 shorts = 12.58 MB
    short* Bg = Ag + (size_t)256 * PLANE;        // 12.58 MB

    corr_prepass<<<dim3(512), dim3(256), 0, stream>>>(in1, in2, Ag, Bg);
    corr_mfma<<<dim3(512), dim3(512), 0, stream>>>(Ag, Bg, out);
}

// Round 2
// 146.123 us; speedup vs baseline: 1.4458x; 1.4458x over previous
//
#include <hip/hip_runtime.h>

// Correlation via bf16 MFMA banded Gram.
// out[b, dyp*21+k, y, x] = (1/256) * sum_c in1[b,c,y,x] * in2[b,c,y+2(dyp-10), x+2(k-10)]
// Layouts (workspace): Ag/Bg[b*64+y][par*48+col][c] bf16, x = 2*col+par.
//
// R7 = R6 structure (512-thread / 8-wave, par x 4 dyp-slots, XOR-swizzled Bsh)
// with launch_bounds relaxed (512,4)->(512,2). R6's (512,4) capped VGPR at 64
// -> scratch spills (WRITE_SIZE 35->128MB). Cap 128 fits the ~96-VGPR live set
// and still permits 4 waves/SIMD; LDS (81920B) holds residency at 2 blocks/CU.

typedef short bf16x8 __attribute__((ext_vector_type(8)));
typedef float f32x4  __attribute__((ext_vector_type(4)));

#define PLANE 24576         // shorts per (b,y) plane: 96 rows * 256 c
#define ST    40            // prepass LDS row stride (shorts)

__device__ __forceinline__ short f2bf(float f) {
    union { float f; unsigned u; } x; x.f = f;
    const unsigned u = x.u;
    return (short)((u + 0x7fffu + ((u >> 16) & 1u)) >> 16);
}

// ---------- prepass: fp32 [b][c][y][x] -> bf16 [b*64+y][par*48+col][c] ----------
// block = (sel, b, ytile of 8, ctile of 32ch). Reads 3KB contiguous per channel.
__global__ __launch_bounds__(256)
void corr_prepass(const float* __restrict__ in1, const float* __restrict__ in2,
                  short* __restrict__ dstA, short* __restrict__ dstB) {
    const int bid = blockIdx.x;
    const int sel = bid >> 8;
    const int r   = bid & 255;
    const int b   = r >> 6;
    const int yt  = (r >> 3) & 7;
    const int ct  = r & 7;
    const int c0 = ct * 32, y0 = yt * 8;
    const float* src = sel ? in2 : in1;
    short* dst = sel ? dstB : dstA;

    __shared__ __align__(16) short T[768 * ST];   // [xx = yy*96+x][32c], 61.4 KB
    const int tid = threadIdx.x;

#pragma unroll
    for (int it = 0; it < 3; ++it) {
        const int d = it * 256 + tid;            // [0,768)
        const int g = d / 192;                   // channel octet 0..3
        const int f = d - g * 192;               // float4 index in 8y*96x chunk
        float4 v[8];
#pragma unroll
        for (int j = 0; j < 8; ++j) {
            const int c = c0 + g * 8 + j;
            v[j] = *(const float4*)(src + ((size_t)(b * 256 + c) * 64 + y0) * 96 + 4 * f);
        }
        bf16x8 w0, w1, w2, w3;
#pragma unroll
        for (int j = 0; j < 8; ++j) {
            w0[j] = f2bf(v[j].x); w1[j] = f2bf(v[j].y);
            w2[j] = f2bf(v[j].z); w3[j] = f2bf(v[j].w);
        }
        const int perm = ((g ^ (f & 3)) * 8);
        const int base = 4 * f * ST + perm;
        *(bf16x8*)&T[base]          = w0;
        *(bf16x8*)&T[base + ST]     = w1;
        *(bf16x8*)&T[base + 2*ST]   = w2;
        *(bf16x8*)&T[base + 3*ST]   = w3;
    }
    __syncthreads();

#pragma unroll
    for (int it = 0; it < 12; ++it) {
        const int D  = it * 256 + tid;           // [0,3072)
        const int Rl = D >> 2, gp = D & 3;
        const int yy  = Rl / 96;
        const int rl  = Rl - yy * 96;
        const int par = rl / 48;
        const int col = rl - par * 48;
        const int x   = 2 * col + par;
        const int xx  = yy * 96 + x;
        const int perm = ((gp ^ ((xx >> 2) & 3)) * 8);
        const bf16x8 w = *(const bf16x8*)&T[xx * ST + perm];
        const size_t Rg = (size_t)(b * 64 + y0 + yy) * 96 + par * 48 + col;
        *(bf16x8*)(dst + Rg * 256 + c0 + gp * 8) = w;
    }
}

// ---------- main kernel: 512 threads = 8 waves = par(2) x slot(4) ----------
__global__ __launch_bounds__(512, 2)
void corr_mfma(const short* __restrict__ Ag, const short* __restrict__ Bg,
               float* __restrict__ out) {
    const int bid = blockIdx.x;                  // [0,512)
    const int pg  = bid >> 8;
    const int by2 = bid & 255;
    const int b = by2 >> 6, y2 = by2 & 63;
    const int p0 = pg ? 3 : 0, p1 = pg ? 6 : 3;  // dyp = 4p+slot: pg0 0..11, pg1 12..23

    const int tid  = threadIdx.x;
    const int lane = tid & 63, w = tid >> 6;     // w in [0,8)
    const int par  = w & 1, slot = w >> 1;       // slot in [0,4)
    const int n    = lane & 15, q = lane >> 4;

    __shared__ __align__(16) short Bsh[96 * 256];    // 49152 B, XOR-swizzled rows
    __shared__ __align__(16) float scr[4][21 * 97];  // 32592 B

    // stage B(b,y2) ONCE (swizzled: short_idx ^= (row&7)<<3  ==  byte ^= (row&7)<<4)
    {
        const short* src = Bg + (size_t)by2 * PLANE;
#pragma unroll
        for (int it = 0; it < 6; ++it) {
            const int j   = it * 512 + tid;      // [0,3072)
            const int row = j >> 5;
            const int ofs = (row * 256 + (j & 31) * 8) ^ ((row & 7) << 3);
            *(bf16x8*)&Bsh[ofs] = *(const bf16x8*)(src + j * 8);
        }
    }
    __syncthreads();

    const bool v0 = (n >= 10), v3 = (n < 10);
    const int r0 = par * 48 + (v0 ? (n - 10) : 0);
    const int r1 = par * 48 + n + 6;
    const int r2 = par * 48 + n + 22;
    const int r3 = par * 48 + (v3 ? (n + 38) : 0);

    for (int p = p0; p < p1; ++p) {
        const int dyp = 4 * p + slot;
        const int y   = y2 + 20 - 2 * dyp;
        const bool live = (dyp < 21) && (y >= 0) && (y < 64);

        f32x4 acc[9];
#pragma unroll
        for (int t2 = 0; t2 < 9; ++t2) acc[t2] = (f32x4)0.0f;

        if (live) {
            // A-fragments direct from global (dense 64B-line gather, L2/L3-resident)
            const short* Ap = Ag + ((size_t)(b * 64 + y) * 96 + par * 48) * 256;
            bf16x8 af[3][8];
#pragma unroll
            for (int ks = 0; ks < 8; ++ks)
#pragma unroll
                for (int Xi = 0; Xi < 3; ++Xi)
                    af[Xi][ks] = *(const bf16x8*)(Ap + (Xi * 16 + n) * 256 + ks * 32 + q * 8);

#pragma unroll
            for (int ks = 0; ks < 8; ++ks) {
                const int ko = ks * 32 + q * 8;
                bf16x8 b0 = *(const bf16x8*)&Bsh[(r0 * 256 + ko) ^ ((r0 & 7) << 3)]; if (!v0) b0 = 0;
                bf16x8 b1 = *(const bf16x8*)&Bsh[(r1 * 256 + ko) ^ ((r1 & 7) << 3)];
                bf16x8 b2 = *(const bf16x8*)&Bsh[(r2 * 256 + ko) ^ ((r2 & 7) << 3)];
                bf16x8 b3 = *(const bf16x8*)&Bsh[(r3 * 256 + ko) ^ ((r3 & 7) << 3)]; if (!v3) b3 = 0;
                acc[0] = __builtin_amdgcn_mfma_f32_16x16x32_bf16(af[0][ks], b0, acc[0], 0, 0, 0);
                acc[1] = __builtin_amdgcn_mfma_f32_16x16x32_bf16(af[0][ks], b1, acc[1], 0, 0, 0);
                acc[2] = __builtin_amdgcn_mfma_f32_16x16x32_bf16(af[0][ks], b2, acc[2], 0, 0, 0);
                acc[3] = __builtin_amdgcn_mfma_f32_16x16x32_bf16(af[1][ks], b1, acc[3], 0, 0, 0);
                acc[4] = __builtin_amdgcn_mfma_f32_16x16x32_bf16(af[1][ks], b2, acc[4], 0, 0, 0);
                acc[5] = __builtin_amdgcn_mfma_f32_16x16x32_bf16(af[1][ks], b3, acc[5], 0, 0, 0);
                acc[6] = __builtin_amdgcn_mfma_f32_16x16x32_bf16(af[2][ks], b2, acc[6], 0, 0, 0);
                acc[7] = __builtin_amdgcn_mfma_f32_16x16x32_bf16(af[2][ks], b3, acc[7], 0, 0, 0);
                // acc[8] = (X2,U4): all B cols OOB -> stays zero (real zero outputs)
            }

            // scatter C tiles into scratch at (k, x=2*xe+par)
            float* sc = scr[slot];
            const int mb = q * 4;
#pragma unroll
            for (int t2 = 0; t2 < 9; ++t2) {
                const int Xi = (t2 < 3) ? 0 : (t2 < 6 ? 1 : 2);
                constexpr int UJ[9] = {0, 1, 2, 1, 2, 3, 2, 3, 4};
                const int ub = UJ[t2] * 16;
#pragma unroll
                for (int rr = 0; rr < 4; ++rr) {
                    const int xe = Xi * 16 + mb + rr;
                    const int k  = ub + n - xe;
                    if ((unsigned)k < 21u)
                        sc[k * 97 + 2 * xe + par] = acc[t2][rr];
                }
            }
        }
        __syncthreads();

        // cooperative coalesced store of all 4 slots' dyps
#pragma unroll
        for (int it = 0; it < 16; ++it) {
            const int e = it * 512 + tid;        // [0,8192), valid < 8064
            if (e < 8064) {
                const int s  = e / 2016;
                const int f  = e - s * 2016;
                const int k  = f / 96;
                const int x  = f - k * 96;
                const int dd = 4 * p + s;
                const int yd = y2 + 20 - 2 * dd;
                if (dd < 21 && yd >= 0 && yd < 64)
                    out[((size_t)(b * 441 + dd * 21 + k) * 64 + yd) * 96 + x] =
                        scr[s][k * 97 + x] * (1.0f / 256.0f);
            }
        }
        __syncthreads();
    }
}

extern "C" void kernel_launch(void* const* d_in, const int* in_sizes, int n_in,
                              void* d_out, int out_size, void* d_ws, size_t ws_size,
                              hipStream_t stream) {
    const float* in1 = (const float*)d_in[0];
    const float* in2 = (const float*)d_in[1];
    float* out = (float*)d_out;

    short* Ag = (short*)d_ws;                    // 256 planes * 24576 shorts = 12.58 MB
    short* Bg = Ag + (size_t)256 * PLANE;        // 12.58 MB

    corr_prepass<<<dim3(512), dim3(256), 0, stream>>>(in1, in2, Ag, Bg);
    corr_mfma<<<dim3(512), dim3(512), 0, stream>>>(Ag, Bg, out);
}

// Round 3
// 145.298 us; speedup vs baseline: 1.4540x; 1.0057x over previous
//
#include <hip/hip_runtime.h>

// Correlation via bf16 MFMA banded Gram.
// out[b, dyp*21+k, y, x] = (1/256) * sum_c in1[b,c,y,x] * in2[b,c,y+2(dyp-10), x+2(k-10)]
// Layouts (workspace): Ag/Bg[b*64+y][par*48+col][c] bf16, x = 2*col+par.
//
// R8 = R7 + XCD-chunked block swizzle in corr_mfma.
// R7 evidence: FETCH_SIZE 109MB ~= 8 x Ag(12.58MB) -> every XCD pulled the whole
// A array through its private L2 (readers of one A-plane were round-robined
// across XCDs). Grid 512 = 8 XCDs x 64 and logical space = 8 (pg,b)-chunks of
// 64 y2-blocks; chunking makes each XCD's working set = one batch's A+B planes
// (~6.3MB, ~L2-resident). bid = (hw&7)*64 + (hw>>3), bijective for 512 blocks.

typedef short bf16x8 __attribute__((ext_vector_type(8)));
typedef float f32x4  __attribute__((ext_vector_type(4)));

#define PLANE 24576         // shorts per (b,y) plane: 96 rows * 256 c
#define ST    40            // prepass LDS row stride (shorts)

__device__ __forceinline__ short f2bf(float f) {
    union { float f; unsigned u; } x; x.f = f;
    const unsigned u = x.u;
    return (short)((u + 0x7fffu + ((u >> 16) & 1u)) >> 16);
}

// ---------- prepass: fp32 [b][c][y][x] -> bf16 [b*64+y][par*48+col][c] ----------
// block = (sel, b, ytile of 8, ctile of 32ch). Reads 3KB contiguous per channel.
// Streaming, no inter-block reuse -> no XCD swizzle (T1 null on streaming ops).
__global__ __launch_bounds__(256)
void corr_prepass(const float* __restrict__ in1, const float* __restrict__ in2,
                  short* __restrict__ dstA, short* __restrict__ dstB) {
    const int bid = blockIdx.x;
    const int sel = bid >> 8;
    const int r   = bid & 255;
    const int b   = r >> 6;
    const int yt  = (r >> 3) & 7;
    const int ct  = r & 7;
    const int c0 = ct * 32, y0 = yt * 8;
    const float* src = sel ? in2 : in1;
    short* dst = sel ? dstB : dstA;

    __shared__ __align__(16) short T[768 * ST];   // [xx = yy*96+x][32c], 61.4 KB
    const int tid = threadIdx.x;

#pragma unroll
    for (int it = 0; it < 3; ++it) {
        const int d = it * 256 + tid;            // [0,768)
        const int g = d / 192;                   // channel octet 0..3
        const int f = d - g * 192;               // float4 index in 8y*96x chunk
        float4 v[8];
#pragma unroll
        for (int j = 0; j < 8; ++j) {
            const int c = c0 + g * 8 + j;
            v[j] = *(const float4*)(src + ((size_t)(b * 256 + c) * 64 + y0) * 96 + 4 * f);
        }
        bf16x8 w0, w1, w2, w3;
#pragma unroll
        for (int j = 0; j < 8; ++j) {
            w0[j] = f2bf(v[j].x); w1[j] = f2bf(v[j].y);
            w2[j] = f2bf(v[j].z); w3[j] = f2bf(v[j].w);
        }
        const int perm = ((g ^ (f & 3)) * 8);
        const int base = 4 * f * ST + perm;
        *(bf16x8*)&T[base]          = w0;
        *(bf16x8*)&T[base + ST]     = w1;
        *(bf16x8*)&T[base + 2*ST]   = w2;
        *(bf16x8*)&T[base + 3*ST]   = w3;
    }
    __syncthreads();

#pragma unroll
    for (int it = 0; it < 12; ++it) {
        const int D  = it * 256 + tid;           // [0,3072)
        const int Rl = D >> 2, gp = D & 3;
        const int yy  = Rl / 96;
        const int rl  = Rl - yy * 96;
        const int par = rl / 48;
        const int col = rl - par * 48;
        const int x   = 2 * col + par;
        const int xx  = yy * 96 + x;
        const int perm = ((gp ^ ((xx >> 2) & 3)) * 8);
        const bf16x8 w = *(const bf16x8*)&T[xx * ST + perm];
        const size_t Rg = (size_t)(b * 64 + y0 + yy) * 96 + par * 48 + col;
        *(bf16x8*)(dst + Rg * 256 + c0 + gp * 8) = w;
    }
}

// ---------- main kernel: 512 threads = 8 waves = par(2) x slot(4) ----------
__global__ __launch_bounds__(512, 2)
void corr_mfma(const short* __restrict__ Ag, const short* __restrict__ Bg,
               float* __restrict__ out) {
    // XCD-chunked swizzle: hw bid round-robins across 8 XCDs; give each XCD
    // one contiguous logical chunk of 64 = one (pg,b) pair.
    const int bhw = blockIdx.x;                  // [0,512)
    const int bid = ((bhw & 7) << 6) | (bhw >> 3);
    const int pg  = bid >> 8;
    const int by2 = bid & 255;
    const int b = by2 >> 6, y2 = by2 & 63;
    const int p0 = pg ? 3 : 0, p1 = pg ? 6 : 3;  // dyp = 4p+slot: pg0 0..11, pg1 12..23

    const int tid  = threadIdx.x;
    const int lane = tid & 63, w = tid >> 6;     // w in [0,8)
    const int par  = w & 1, slot = w >> 1;       // slot in [0,4)
    const int n    = lane & 15, q = lane >> 4;

    __shared__ __align__(16) short Bsh[96 * 256];    // 49152 B, XOR-swizzled rows
    __shared__ __align__(16) float scr[4][21 * 97];  // 32592 B

    // stage B(b,y2) ONCE (swizzled: short_idx ^= (row&7)<<3  ==  byte ^= (row&7)<<4)
    {
        const short* src = Bg + (size_t)by2 * PLANE;
#pragma unroll
        for (int it = 0; it < 6; ++it) {
            const int j   = it * 512 + tid;      // [0,3072)
            const int row = j >> 5;
            const int ofs = (row * 256 + (j & 31) * 8) ^ ((row & 7) << 3);
            *(bf16x8*)&Bsh[ofs] = *(const bf16x8*)(src + j * 8);
        }
    }
    __syncthreads();

    const bool v0 = (n >= 10), v3 = (n < 10);
    const int r0 = par * 48 + (v0 ? (n - 10) : 0);
    const int r1 = par * 48 + n + 6;
    const int r2 = par * 48 + n + 22;
    const int r3 = par * 48 + (v3 ? (n + 38) : 0);

    for (int p = p0; p < p1; ++p) {
        const int dyp = 4 * p + slot;
        const int y   = y2 + 20 - 2 * dyp;
        const bool live = (dyp < 21) && (y >= 0) && (y < 64);

        f32x4 acc[9];
#pragma unroll
        for (int t2 = 0; t2 < 9; ++t2) acc[t2] = (f32x4)0.0f;

        if (live) {
            // A-fragments direct from global (dense 64B-line gather, now L2-resident)
            const short* Ap = Ag + ((size_t)(b * 64 + y) * 96 + par * 48) * 256;
            bf16x8 af[3][8];
#pragma unroll
            for (int ks = 0; ks < 8; ++ks)
#pragma unroll
                for (int Xi = 0; Xi < 3; ++Xi)
                    af[Xi][ks] = *(const bf16x8*)(Ap + (Xi * 16 + n) * 256 + ks * 32 + q * 8);

#pragma unroll
            for (int ks = 0; ks < 8; ++ks) {
                const int ko = ks * 32 + q * 8;
                bf16x8 b0 = *(const bf16x8*)&Bsh[(r0 * 256 + ko) ^ ((r0 & 7) << 3)]; if (!v0) b0 = 0;
                bf16x8 b1 = *(const bf16x8*)&Bsh[(r1 * 256 + ko) ^ ((r1 & 7) << 3)];
                bf16x8 b2 = *(const bf16x8*)&Bsh[(r2 * 256 + ko) ^ ((r2 & 7) << 3)];
                bf16x8 b3 = *(const bf16x8*)&Bsh[(r3 * 256 + ko) ^ ((r3 & 7) << 3)]; if (!v3) b3 = 0;
                acc[0] = __builtin_amdgcn_mfma_f32_16x16x32_bf16(af[0][ks], b0, acc[0], 0, 0, 0);
                acc[1] = __builtin_amdgcn_mfma_f32_16x16x32_bf16(af[0][ks], b1, acc[1], 0, 0, 0);
                acc[2] = __builtin_amdgcn_mfma_f32_16x16x32_bf16(af[0][ks], b2, acc[2], 0, 0, 0);
                acc[3] = __builtin_amdgcn_mfma_f32_16x16x32_bf16(af[1][ks], b1, acc[3], 0, 0, 0);
                acc[4] = __builtin_amdgcn_mfma_f32_16x16x32_bf16(af[1][ks], b2, acc[4], 0, 0, 0);
                acc[5] = __builtin_amdgcn_mfma_f32_16x16x32_bf16(af[1][ks], b3, acc[5], 0, 0, 0);
                acc[6] = __builtin_amdgcn_mfma_f32_16x16x32_bf16(af[2][ks], b2, acc[6], 0, 0, 0);
                acc[7] = __builtin_amdgcn_mfma_f32_16x16x32_bf16(af[2][ks], b3, acc[7], 0, 0, 0);
                // acc[8] = (X2,U4): all B cols OOB -> stays zero (real zero outputs)
            }

            // scatter C tiles into scratch at (k, x=2*xe+par)
            float* sc = scr[slot];
            const int mb = q * 4;
#pragma unroll
            for (int t2 = 0; t2 < 9; ++t2) {
                const int Xi = (t2 < 3) ? 0 : (t2 < 6 ? 1 : 2);
                constexpr int UJ[9] = {0, 1, 2, 1, 2, 3, 2, 3, 4};
                const int ub = UJ[t2] * 16;
#pragma unroll
                for (int rr = 0; rr < 4; ++rr) {
                    const int xe = Xi * 16 + mb + rr;
                    const int k  = ub + n - xe;
                    if ((unsigned)k < 21u)
                        sc[k * 97 + 2 * xe + par] = acc[t2][rr];
                }
            }
        }
        __syncthreads();

        // cooperative coalesced store of all 4 slots' dyps
#pragma unroll
        for (int it = 0; it < 16; ++it) {
            const int e = it * 512 + tid;        // [0,8192), valid < 8064
            if (e < 8064) {
                const int s  = e / 2016;
                const int f  = e - s * 2016;
                const int k  = f / 96;
                const int x  = f - k * 96;
                const int dd = 4 * p + s;
                const int yd = y2 + 20 - 2 * dd;
                if (dd < 21 && yd >= 0 && yd < 64)
                    out[((size_t)(b * 441 + dd * 21 + k) * 64 + yd) * 96 + x] =
                        scr[s][k * 97 + x] * (1.0f / 256.0f);
            }
        }
        __syncthreads();
    }
}

extern "C" void kernel_launch(void* const* d_in, const int* in_sizes, int n_in,
                              void* d_out, int out_size, void* d_ws, size_t ws_size,
                              hipStream_t stream) {
    const float* in1 = (const float*)d_in[0];
    const float* in2 = (const float*)d_in[1];
    float* out = (float*)d_out;

    short* Ag = (short*)d_ws;                    // 256 planes * 24576 shorts = 12.58 MB
    short* Bg = Ag + (size_t)256 * PLANE;        // 12.58 MB

    corr_prepass<<<dim3(512), dim3(256), 0, stream>>>(in1, in2, Ag, Bg);
    corr_mfma<<<dim3(512), dim3(512), 0, stream>>>(Ag, Bg, out);
}

// Round 5
// 142.174 us; speedup vs baseline: 1.4860x; 1.0220x over previous
//
#include <hip/hip_runtime.h>

// Correlation via bf16 MFMA banded Gram.
// out[b, dyp*21+k, y, x] = (1/256) * sum_c in1[b,c,y,x] * in2[b,c,y+2(dyp-10), x+2(k-10)]
// Layouts (workspace): Ag/Bg[b*64+y][par*48+col][c] bf16, x = 2*col+par.
//
// R9 = R8 + (a) barrier-free main rounds via wave-private scr, (b) 512-thread prepass.
// R8 evidence: all pipes idle (Mfma 6.4 / VALU 13 / HBM 15%), FETCH already ideal
// -> lockstep convoy from 2 __syncthreads per round (each drains vmcnt(0)).
// scr becomes per-wave [xe*21+k] (xe-major: scatter <=2-way banks, k-major read
// conflict-free); stores per-wave at x-stride-2, par-sibling fills the other
// half-line via L2. LDS 49152 + 8*1008*4 = 81408 B -> still 2 blocks/CU.
// (R10 resubmit: R9 bench was GPUAcquisitionTimeout; source unchanged.)

typedef short bf16x8 __attribute__((ext_vector_type(8)));
typedef float f32x4  __attribute__((ext_vector_type(4)));

#define PLANE 24576         // shorts per (b,y) plane: 96 rows * 256 c
#define ST    40            // prepass LDS row stride (shorts)

__device__ __forceinline__ short f2bf(float f) {
    union { float f; unsigned u; } x; x.f = f;
    const unsigned u = x.u;
    return (short)((u + 0x7fffu + ((u >> 16) & 1u)) >> 16);
}

// ---------- prepass: fp32 [b][c][y][x] -> bf16 [b*64+y][par*48+col][c] ----------
// block = (sel, b, ytile of 8, ctile of 32ch). Reads 3KB contiguous per channel.
// R9: 512 threads (was 256) -> 16 waves/CU instead of 8; same tile & LDS.
__global__ __launch_bounds__(512)
void corr_prepass(const float* __restrict__ in1, const float* __restrict__ in2,
                  short* __restrict__ dstA, short* __restrict__ dstB) {
    const int bid = blockIdx.x;
    const int sel = bid >> 8;
    const int r   = bid & 255;
    const int b   = r >> 6;
    const int yt  = (r >> 3) & 7;
    const int ct  = r & 7;
    const int c0 = ct * 32, y0 = yt * 8;
    const float* src = sel ? in2 : in1;
    short* dst = sel ? dstB : dstA;

    __shared__ __align__(16) short T[768 * ST];   // [xx = yy*96+x][32c], 61.4 KB
    const int tid = threadIdx.x;

#pragma unroll
    for (int it = 0; it < 2; ++it) {
        const int d = it * 512 + tid;            // [0,1024), use d<768
        if (d < 768) {
            const int g = d / 192;               // channel octet 0..3
            const int f = d - g * 192;           // float4 index in 8y*96x chunk
            float4 v[8];
#pragma unroll
            for (int j = 0; j < 8; ++j) {
                const int c = c0 + g * 8 + j;
                v[j] = *(const float4*)(src + ((size_t)(b * 256 + c) * 64 + y0) * 96 + 4 * f);
            }
            bf16x8 w0, w1, w2, w3;
#pragma unroll
            for (int j = 0; j < 8; ++j) {
                w0[j] = f2bf(v[j].x); w1[j] = f2bf(v[j].y);
                w2[j] = f2bf(v[j].z); w3[j] = f2bf(v[j].w);
            }
            const int perm = ((g ^ (f & 3)) * 8);
            const int base = 4 * f * ST + perm;
            *(bf16x8*)&T[base]          = w0;
            *(bf16x8*)&T[base + ST]     = w1;
            *(bf16x8*)&T[base + 2*ST]   = w2;
            *(bf16x8*)&T[base + 3*ST]   = w3;
        }
    }
    __syncthreads();

#pragma unroll
    for (int it = 0; it < 6; ++it) {
        const int D  = it * 512 + tid;           // [0,3072)
        const int Rl = D >> 2, gp = D & 3;
        const int yy  = Rl / 96;
        const int rl  = Rl - yy * 96;
        const int par = rl / 48;
        const int col = rl - par * 48;
        const int x   = 2 * col + par;
        const int xx  = yy * 96 + x;
        const int perm = ((gp ^ ((xx >> 2) & 3)) * 8);
        const bf16x8 w = *(const bf16x8*)&T[xx * ST + perm];
        const size_t Rg = (size_t)(b * 64 + y0 + yy) * 96 + par * 48 + col;
        *(bf16x8*)(dst + Rg * 256 + c0 + gp * 8) = w;
    }
}

// ---------- main kernel: 512 threads = 8 waves = par(2) x slot(4) ----------
// Barrier-free rounds: each wave owns scr[w], scatters and stores independently.
__global__ __launch_bounds__(512, 2)
void corr_mfma(const short* __restrict__ Ag, const short* __restrict__ Bg,
               float* __restrict__ out) {
    // XCD-chunked swizzle: each XCD gets one contiguous (pg,b) chunk of 64 blocks.
    const int bhw = blockIdx.x;                  // [0,512)
    const int bid = ((bhw & 7) << 6) | (bhw >> 3);
    const int pg  = bid >> 8;
    const int by2 = bid & 255;
    const int b = by2 >> 6, y2 = by2 & 63;
    const int p0 = pg ? 3 : 0, p1 = pg ? 6 : 3;  // dyp = 4p+slot: pg0 0..11, pg1 12..23

    const int tid  = threadIdx.x;
    const int lane = tid & 63, w = tid >> 6;     // w in [0,8)
    const int par  = w & 1, slot = w >> 1;       // slot in [0,4)
    const int n    = lane & 15, q = lane >> 4;

    __shared__ __align__(16) short Bsh[96 * 256];    // 49152 B, XOR-swizzled rows
    __shared__ __align__(16) float scr[8][1008];     // 32256 B, per-wave, xe-major

    // stage B(b,y2) ONCE (swizzled: short_idx ^= (row&7)<<3  ==  byte ^= (row&7)<<4)
    {
        const short* src = Bg + (size_t)by2 * PLANE;
#pragma unroll
        for (int it = 0; it < 6; ++it) {
            const int j   = it * 512 + tid;      // [0,3072)
            const int row = j >> 5;
            const int ofs = (row * 256 + (j & 31) * 8) ^ ((row & 7) << 3);
            *(bf16x8*)&Bsh[ofs] = *(const bf16x8*)(src + j * 8);
        }
    }
    __syncthreads();                             // the ONLY block-wide barrier

    const bool v0 = (n >= 10), v3 = (n < 10);
    const int r0 = par * 48 + (v0 ? (n - 10) : 0);
    const int r1 = par * 48 + n + 6;
    const int r2 = par * 48 + n + 22;
    const int r3 = par * 48 + (v3 ? (n + 38) : 0);

    float* const sc = scr[w];

    for (int p = p0; p < p1; ++p) {
        const int dyp = 4 * p + slot;
        const int y   = y2 + 20 - 2 * dyp;
        const bool live = (dyp < 21) && (y >= 0) && (y < 64);
        if (!live) continue;                     // wave-uniform

        f32x4 acc[9];
#pragma unroll
        for (int t2 = 0; t2 < 9; ++t2) acc[t2] = (f32x4)0.0f;

        // A-fragments direct from global (dense 64B-line gather, L2-resident)
        const short* Ap = Ag + ((size_t)(b * 64 + y) * 96 + par * 48) * 256;
        bf16x8 af[3][8];
#pragma unroll
        for (int ks = 0; ks < 8; ++ks)
#pragma unroll
            for (int Xi = 0; Xi < 3; ++Xi)
                af[Xi][ks] = *(const bf16x8*)(Ap + (Xi * 16 + n) * 256 + ks * 32 + q * 8);

#pragma unroll
        for (int ks = 0; ks < 8; ++ks) {
            const int ko = ks * 32 + q * 8;
            bf16x8 b0 = *(const bf16x8*)&Bsh[(r0 * 256 + ko) ^ ((r0 & 7) << 3)]; if (!v0) b0 = 0;
            bf16x8 b1 = *(const bf16x8*)&Bsh[(r1 * 256 + ko) ^ ((r1 & 7) << 3)];
            bf16x8 b2 = *(const bf16x8*)&Bsh[(r2 * 256 + ko) ^ ((r2 & 7) << 3)];
            bf16x8 b3 = *(const bf16x8*)&Bsh[(r3 * 256 + ko) ^ ((r3 & 7) << 3)]; if (!v3) b3 = 0;
            acc[0] = __builtin_amdgcn_mfma_f32_16x16x32_bf16(af[0][ks], b0, acc[0], 0, 0, 0);
            acc[1] = __builtin_amdgcn_mfma_f32_16x16x32_bf16(af[0][ks], b1, acc[1], 0, 0, 0);
            acc[2] = __builtin_amdgcn_mfma_f32_16x16x32_bf16(af[0][ks], b2, acc[2], 0, 0, 0);
            acc[3] = __builtin_amdgcn_mfma_f32_16x16x32_bf16(af[1][ks], b1, acc[3], 0, 0, 0);
            acc[4] = __builtin_amdgcn_mfma_f32_16x16x32_bf16(af[1][ks], b2, acc[4], 0, 0, 0);
            acc[5] = __builtin_amdgcn_mfma_f32_16x16x32_bf16(af[1][ks], b3, acc[5], 0, 0, 0);
            acc[6] = __builtin_amdgcn_mfma_f32_16x16x32_bf16(af[2][ks], b2, acc[6], 0, 0, 0);
            acc[7] = __builtin_amdgcn_mfma_f32_16x16x32_bf16(af[2][ks], b3, acc[7], 0, 0, 0);
            // acc[8] = (X2,U4): all B cols OOB -> stays zero (real zero outputs)
        }

        // wave-private scatter: sc[xe*21 + k]  (xe-major: <=2-way bank aliasing)
        const int mb = q * 4;
#pragma unroll
        for (int t2 = 0; t2 < 9; ++t2) {
            const int Xi = (t2 < 3) ? 0 : (t2 < 6 ? 1 : 2);
            constexpr int UJ[9] = {0, 1, 2, 1, 2, 3, 2, 3, 4};
            const int ub = UJ[t2] * 16;
#pragma unroll
            for (int rr = 0; rr < 4; ++rr) {
                const int xe = Xi * 16 + mb + rr;
                const int k  = ub + n - xe;
                if ((unsigned)k < 21u)
                    sc[xe * 21 + k] = acc[t2][rr];
            }
        }

        // wave-private store, k-major for x-locality (stride-2; par sibling
        // fills the other half of each line through L2)
        const size_t obase = ((size_t)(b * 441 + dyp * 21) * 64 + y) * 96 + par;
#pragma unroll
        for (int it = 0; it < 16; ++it) {
            const int e = it * 64 + lane;        // [0,1024), valid < 1008
            if (e < 1008) {
                const int k  = e / 48;
                const int xe = e - k * 48;
                out[obase + (size_t)k * 6144 + 2 * xe] = sc[xe * 21 + k] * (1.0f / 256.0f);
            }
        }
    }
}

extern "C" void kernel_launch(void* const* d_in, const int* in_sizes, int n_in,
                              void* d_out, int out_size, void* d_ws, size_t ws_size,
                              hipStream_t stream) {
    const float* in1 = (const float*)d_in[0];
    const float* in2 = (const float*)d_in[1];
    float* out = (float*)d_out;

    short* Ag = (short*)d_ws;                    // 256 planes * 24576 shorts = 12.58 MB
    short* Bg = Ag + (size_t)256 * PLANE;        // 12.58 MB

    corr_prepass<<<dim3(512), dim3(512), 0, stream>>>(in1, in2, Ag, Bg);
    corr_mfma<<<dim3(512), dim3(512), 0, stream>>>(Ag, Bg, out);
}

// Round 7
// 142.005 us; speedup vs baseline: 1.4877x; 1.0012x over previous
//
#include <hip/hip_runtime.h>

// Correlation via bf16 MFMA banded Gram.
// out[b, dyp*21+k, y, x] = (1/256) * sum_c in1[b,c,y,x] * in2[b,c,y+2(dyp-10), x+2(k-10)]
// Layouts (workspace): Ag/Bg[b*64+y][par*48+col][c] bf16, x = 2*col+par.
//
// R11 = R9 + explicit 4-deep rotating A-prefetch in the MFMA loop.
// R9 evidence: VGPR=88 < af[3][8]'s 96 -> compiler sank A-loads into the MFMA
// loop (one ks-step in flight) -> each of 24 ks-steps exposes full L2/L3 load
// latency; duration set by this per-wave serial chain (occupancy fell 18.6->14.6
// with waves exiting early, yet time ~flat). Fix: 4 named ks-step buffers,
// full unroll (static indices), prefetch distance 3; store phase split into
// gather-16-regs then store-16 to unserialize the scr read->store chain.
// (R12 resubmit: R11 bench was GPUAcquisitionTimeout; source unchanged.)

typedef short bf16x8 __attribute__((ext_vector_type(8)));
typedef float f32x4  __attribute__((ext_vector_type(4)));

#define PLANE 24576         // shorts per (b,y) plane: 96 rows * 256 c
#define ST    40            // prepass LDS row stride (shorts)

__device__ __forceinline__ short f2bf(float f) {
    union { float f; unsigned u; } x; x.f = f;
    const unsigned u = x.u;
    return (short)((u + 0x7fffu + ((u >> 16) & 1u)) >> 16);
}

// ---------- prepass: fp32 [b][c][y][x] -> bf16 [b*64+y][par*48+col][c] ----------
// block = (sel, b, ytile of 8, ctile of 32ch). Reads 3KB contiguous per channel.
__global__ __launch_bounds__(512)
void corr_prepass(const float* __restrict__ in1, const float* __restrict__ in2,
                  short* __restrict__ dstA, short* __restrict__ dstB) {
    const int bid = blockIdx.x;
    const int sel = bid >> 8;
    const int r   = bid & 255;
    const int b   = r >> 6;
    const int yt  = (r >> 3) & 7;
    const int ct  = r & 7;
    const int c0 = ct * 32, y0 = yt * 8;
    const float* src = sel ? in2 : in1;
    short* dst = sel ? dstB : dstA;

    __shared__ __align__(16) short T[768 * ST];   // [xx = yy*96+x][32c], 61.4 KB
    const int tid = threadIdx.x;

#pragma unroll
    for (int it = 0; it < 2; ++it) {
        const int d = it * 512 + tid;            // [0,1024), use d<768
        if (d < 768) {
            const int g = d / 192;               // channel octet 0..3
            const int f = d - g * 192;           // float4 index in 8y*96x chunk
            float4 v[8];
#pragma unroll
            for (int j = 0; j < 8; ++j) {
                const int c = c0 + g * 8 + j;
                v[j] = *(const float4*)(src + ((size_t)(b * 256 + c) * 64 + y0) * 96 + 4 * f);
            }
            bf16x8 w0, w1, w2, w3;
#pragma unroll
            for (int j = 0; j < 8; ++j) {
                w0[j] = f2bf(v[j].x); w1[j] = f2bf(v[j].y);
                w2[j] = f2bf(v[j].z); w3[j] = f2bf(v[j].w);
            }
            const int perm = ((g ^ (f & 3)) * 8);
            const int base = 4 * f * ST + perm;
            *(bf16x8*)&T[base]          = w0;
            *(bf16x8*)&T[base + ST]     = w1;
            *(bf16x8*)&T[base + 2*ST]   = w2;
            *(bf16x8*)&T[base + 3*ST]   = w3;
        }
    }
    __syncthreads();

#pragma unroll
    for (int it = 0; it < 6; ++it) {
        const int D  = it * 512 + tid;           // [0,3072)
        const int Rl = D >> 2, gp = D & 3;
        const int yy  = Rl / 96;
        const int rl  = Rl - yy * 96;
        const int par = rl / 48;
        const int col = rl - par * 48;
        const int x   = 2 * col + par;
        const int xx  = yy * 96 + x;
        const int perm = ((gp ^ ((xx >> 2) & 3)) * 8);
        const bf16x8 w = *(const bf16x8*)&T[xx * ST + perm];
        const size_t Rg = (size_t)(b * 64 + y0 + yy) * 96 + par * 48 + col;
        *(bf16x8*)(dst + Rg * 256 + c0 + gp * 8) = w;
    }
}

// ---------- main kernel: 512 threads = 8 waves = par(2) x slot(4) ----------
// Barrier-free rounds; wave-private scr; 4-deep rotating A-prefetch.
__global__ __launch_bounds__(512, 2)
void corr_mfma(const short* __restrict__ Ag, const short* __restrict__ Bg,
               float* __restrict__ out) {
    // XCD-chunked swizzle: each XCD gets one contiguous (pg,b) chunk of 64 blocks.
    const int bhw = blockIdx.x;                  // [0,512)
    const int bid = ((bhw & 7) << 6) | (bhw >> 3);
    const int pg  = bid >> 8;
    const int by2 = bid & 255;
    const int b = by2 >> 6, y2 = by2 & 63;
    const int p0 = pg ? 3 : 0, p1 = pg ? 6 : 3;  // dyp = 4p+slot: pg0 0..11, pg1 12..23

    const int tid  = threadIdx.x;
    const int lane = tid & 63, w = tid >> 6;     // w in [0,8)
    const int par  = w & 1, slot = w >> 1;       // slot in [0,4)
    const int n    = lane & 15, q = lane >> 4;

    __shared__ __align__(16) short Bsh[96 * 256];    // 49152 B, XOR-swizzled rows
    __shared__ __align__(16) float scr[8][1008];     // 32256 B, per-wave, xe-major

    // stage B(b,y2) ONCE (swizzled: short_idx ^= (row&7)<<3  ==  byte ^= (row&7)<<4)
    {
        const short* src = Bg + (size_t)by2 * PLANE;
#pragma unroll
        for (int it = 0; it < 6; ++it) {
            const int j   = it * 512 + tid;      // [0,3072)
            const int row = j >> 5;
            const int ofs = (row * 256 + (j & 31) * 8) ^ ((row & 7) << 3);
            *(bf16x8*)&Bsh[ofs] = *(const bf16x8*)(src + j * 8);
        }
    }
    __syncthreads();                             // the ONLY block-wide barrier

    const bool v0 = (n >= 10), v3 = (n < 10);
    const int r0 = par * 48 + (v0 ? (n - 10) : 0);
    const int r1 = par * 48 + n + 6;
    const int r2 = par * 48 + n + 22;
    const int r3 = par * 48 + (v3 ? (n + 38) : 0);

    float* const sc = scr[w];

    for (int p = p0; p < p1; ++p) {
        const int dyp = 4 * p + slot;
        const int y   = y2 + 20 - 2 * dyp;
        const bool live = (dyp < 21) && (y >= 0) && (y < 64);
        if (!live) continue;                     // wave-uniform

        f32x4 acc[9];
#pragma unroll
        for (int t2 = 0; t2 < 9; ++t2) acc[t2] = (f32x4)0.0f;

        // Per-lane A base; all 24 loads are static element offsets from it.
        // (Xi,ks) offset = Xi*4096 + ks*32 shorts.
        const short* Ap = Ag + ((size_t)(b * 64 + y) * 96 + par * 48) * 256
                        + n * 256 + q * 8;

        // 4-deep rotating ks-step buffers (all indices compile-time).
        bf16x8 a0[3], a1[3], a2[3], a3[3];
#define LOADA(buf, ks) \
        buf[0] = *(const bf16x8*)(Ap + 0 * 4096 + (ks) * 32); \
        buf[1] = *(const bf16x8*)(Ap + 1 * 4096 + (ks) * 32); \
        buf[2] = *(const bf16x8*)(Ap + 2 * 4096 + (ks) * 32);

        LOADA(a0, 0) LOADA(a1, 1) LOADA(a2, 2) LOADA(a3, 3)

#define STEP(ks, ab, PF) { \
        const int ko = (ks) * 32 + q * 8; \
        bf16x8 b0 = *(const bf16x8*)&Bsh[(r0 * 256 + ko) ^ ((r0 & 7) << 3)]; if (!v0) b0 = 0; \
        bf16x8 b1 = *(const bf16x8*)&Bsh[(r1 * 256 + ko) ^ ((r1 & 7) << 3)]; \
        bf16x8 b2 = *(const bf16x8*)&Bsh[(r2 * 256 + ko) ^ ((r2 & 7) << 3)]; \
        bf16x8 b3 = *(const bf16x8*)&Bsh[(r3 * 256 + ko) ^ ((r3 & 7) << 3)]; if (!v3) b3 = 0; \
        acc[0] = __builtin_amdgcn_mfma_f32_16x16x32_bf16(ab[0], b0, acc[0], 0, 0, 0); \
        acc[1] = __builtin_amdgcn_mfma_f32_16x16x32_bf16(ab[0], b1, acc[1], 0, 0, 0); \
        acc[2] = __builtin_amdgcn_mfma_f32_16x16x32_bf16(ab[0], b2, acc[2], 0, 0, 0); \
        acc[3] = __builtin_amdgcn_mfma_f32_16x16x32_bf16(ab[1], b1, acc[3], 0, 0, 0); \
        acc[4] = __builtin_amdgcn_mfma_f32_16x16x32_bf16(ab[1], b2, acc[4], 0, 0, 0); \
        acc[5] = __builtin_amdgcn_mfma_f32_16x16x32_bf16(ab[1], b3, acc[5], 0, 0, 0); \
        acc[6] = __builtin_amdgcn_mfma_f32_16x16x32_bf16(ab[2], b2, acc[6], 0, 0, 0); \
        acc[7] = __builtin_amdgcn_mfma_f32_16x16x32_bf16(ab[2], b3, acc[7], 0, 0, 0); \
        if (PF) { LOADA(ab, (ks) + 4) } \
    }
        // acc[8] = (X2,U4): all B cols OOB -> stays zero (real zero outputs)

        STEP(0, a0, 1) STEP(1, a1, 1) STEP(2, a2, 1) STEP(3, a3, 1)
        STEP(4, a0, 0) STEP(5, a1, 0) STEP(6, a2, 0) STEP(7, a3, 0)
#undef STEP
#undef LOADA

        // wave-private scatter: sc[xe*21 + k]  (xe-major: <=2-way bank aliasing)
        const int mb = q * 4;
#pragma unroll
        for (int t2 = 0; t2 < 9; ++t2) {
            const int Xi = (t2 < 3) ? 0 : (t2 < 6 ? 1 : 2);
            constexpr int UJ[9] = {0, 1, 2, 1, 2, 3, 2, 3, 4};
            const int ub = UJ[t2] * 16;
#pragma unroll
            for (int rr = 0; rr < 4; ++rr) {
                const int xe = Xi * 16 + mb + rr;
                const int k  = ub + n - xe;
                if ((unsigned)k < 21u)
                    sc[xe * 21 + k] = acc[t2][rr];
            }
        }

        // wave-private store: gather 16 values first (breaks read->store chain),
        // then 16 stores. k-major for x-locality; stride-2, par sibling fills
        // the other half of each line through L2.
        const size_t obase = ((size_t)(b * 441 + dyp * 21) * 64 + y) * 96 + par;
        float vals[16];
#pragma unroll
        for (int it = 0; it < 16; ++it) {
            const int e = it * 64 + lane;        // [0,1024), valid < 1008
            vals[it] = (e < 1008) ? sc[(e % 48) * 21 + (e / 48)] : 0.0f;
        }
#pragma unroll
        for (int it = 0; it < 16; ++it) {
            const int e = it * 64 + lane;
            if (e < 1008) {
                const int k  = e / 48;
                const int xe = e - k * 48;
                out[obase + (size_t)k * 6144 + 2 * xe] = vals[it] * (1.0f / 256.0f);
            }
        }
    }
}

extern "C" void kernel_launch(void* const* d_in, const int* in_sizes, int n_in,
                              void* d_out, int out_size, void* d_ws, size_t ws_size,
                              hipStream_t stream) {
    const float* in1 = (const float*)d_in[0];
    const float* in2 = (const float*)d_in[1];
    float* out = (float*)d_out;

    short* Ag = (short*)d_ws;                    // 256 planes * 24576 shorts = 12.58 MB
    short* Bg = Ag + (size_t)256 * PLANE;        // 12.58 MB

    corr_prepass<<<dim3(512), dim3(512), 0, stream>>>(in1, in2, Ag, Bg);
    corr_mfma<<<dim3(512), dim3(512), 0, stream>>>(Ag, Bg, out);
}